// Round 1
// baseline (278.752 us; speedup 1.0000x reference)
//
#include <hip/hip_runtime.h>

static constexpr int KH = 15, KW = 15;
static constexpr int HI = 4096, WI = 4096;
static constexpr int HO = HI - KH + 1, WO = WI - KW + 1;   // 4082 x 4082
static constexpr int TM = 64, TN = 64;                     // output tile per block
static constexpr int LROWS = TM + KH - 1;                  // 78
static constexpr int LCOLS = TN + KW - 1;                  // 78
static constexpr int LSTR  = 84;                           // padded LDS row stride (mult of 4 -> 16B-aligned float4)

__global__ __launch_bounds__(256, 4)
void conv2d_15x15(const float* __restrict__ x,
                  const float* __restrict__ w,
                  const float* __restrict__ bias,
                  float* __restrict__ out) {
  __shared__ float sx[LROWS * LSTR];   // 78*84*4 = 26,208 B
  __shared__ float sw[KH * KW];        // 900 B

  const int tid  = threadIdx.x;
  const int row0 = blockIdx.y * TM;
  const int col0 = blockIdx.x * TN;

  // stage weights (broadcast-read later; same-address LDS reads are free)
  if (tid < KH * KW) sw[tid] = w[tid];

  // stage 78x78 input tile, coalesced (c fastest), zero-fill out-of-range halo
  for (int i = tid; i < LROWS * LCOLS; i += 256) {
    const int r = i / LCOLS;
    const int c = i - r * LCOLS;
    const int gr = row0 + r;
    const int gc = col0 + c;
    float v = 0.0f;
    if (gr < HI && gc < WI) v = x[gr * WI + gc];
    sx[r * LSTR + c] = v;
  }
  __syncthreads();

  const int tx = tid & 15;
  const int ty = tid >> 4;
  const int xb = tx * 4;          // 16B-aligned LDS column base
  const int yb = ty * 4;

  float acc[4][4];
  #pragma unroll
  for (int r = 0; r < 4; ++r)
    #pragma unroll
    for (int c = 0; c < 4; ++c) acc[r][c] = 0.0f;

  for (int kh = 0; kh < KH; ++kh) {
    float wr[KW];
    #pragma unroll
    for (int kw = 0; kw < KW; ++kw) wr[kw] = sw[kh * KW + kw];

    #pragma unroll
    for (int r = 0; r < 4; ++r) {
      const float* rowp = &sx[(yb + r + kh) * LSTR + xb];
      float xr[18];
      const float4 v0 = *(const float4*)(rowp + 0);
      const float4 v1 = *(const float4*)(rowp + 4);
      const float4 v2 = *(const float4*)(rowp + 8);
      const float4 v3 = *(const float4*)(rowp + 12);
      const float2 v4 = *(const float2*)(rowp + 16);
      xr[0]=v0.x;  xr[1]=v0.y;  xr[2]=v0.z;  xr[3]=v0.w;
      xr[4]=v1.x;  xr[5]=v1.y;  xr[6]=v1.z;  xr[7]=v1.w;
      xr[8]=v2.x;  xr[9]=v2.y;  xr[10]=v2.z; xr[11]=v2.w;
      xr[12]=v3.x; xr[13]=v3.y; xr[14]=v3.z; xr[15]=v3.w;
      xr[16]=v4.x; xr[17]=v4.y;

      #pragma unroll
      for (int kw = 0; kw < KW; ++kw) {
        const float wv = wr[kw];
        acc[r][0] = fmaf(xr[kw + 0], wv, acc[r][0]);
        acc[r][1] = fmaf(xr[kw + 1], wv, acc[r][1]);
        acc[r][2] = fmaf(xr[kw + 2], wv, acc[r][2]);
        acc[r][3] = fmaf(xr[kw + 3], wv, acc[r][3]);
      }
    }
  }

  const float b = bias[0];
  #pragma unroll
  for (int r = 0; r < 4; ++r) {
    const int oy = row0 + yb + r;
    if (oy < HO) {
      #pragma unroll
      for (int c = 0; c < 4; ++c) {
        const int ox = col0 + xb + c;
        if (ox < WO) out[oy * WO + ox] = acc[r][c] + b;
      }
    }
  }
}

extern "C" void kernel_launch(void* const* d_in, const int* in_sizes, int n_in,
                              void* d_out, int out_size, void* d_ws, size_t ws_size,
                              hipStream_t stream) {
  const float* x    = (const float*)d_in[0];
  const float* w    = (const float*)d_in[1];
  const float* bias = (const float*)d_in[2];
  float* out        = (float*)d_out;

  dim3 grid((WO + TN - 1) / TN, (HO + TM - 1) / TM);  // 64 x 64 blocks
  conv2d_15x15<<<grid, dim3(256, 1, 1), 0, stream>>>(x, w, bias, out);
}

// Round 2
// 45.491 us; speedup vs baseline: 6.1276x; 6.1276x over previous
//
#include <hip/hip_runtime.h>

typedef short bf16x8 __attribute__((ext_vector_type(8)));
typedef float f32x4  __attribute__((ext_vector_type(4)));

static constexpr int KH = 15, KW = 15;
static constexpr int HI = 4096, WI = 4096;
static constexpr int HO = HI - KH + 1, WO = WI - KW + 1;   // 4082 x 4082
static constexpr int TM = 64, TN = 64;                     // output tile per block
static constexpr int LR   = TM + KH - 1;                   // 78 staged rows
static constexpr int LC   = 80;                            // staged bf16 cols (A reads touch up to col 79)
static constexpr int LSTR = 88;                            // bf16/row: 176 B -> 16B-aligned, 44 dw % 32 = 12 -> 2-way max (free)

__device__ __forceinline__ unsigned int f2bf(float f) {
  // round-to-nearest-even f32 -> bf16 bits (no NaN in this problem)
  unsigned int u = __builtin_bit_cast(unsigned int, f);
  return (u + 0x7FFFu + ((u >> 16) & 1u)) >> 16;
}

__global__ __launch_bounds__(256, 2)
void conv2d_mfma(const float* __restrict__ x, const float* __restrict__ w,
                 const float* __restrict__ bias, float* __restrict__ out) {
  __shared__ unsigned short sx[LR * LSTR];        // 13,728 B bf16 input tile
  __shared__ float          sw[KH * KW];          // 900 B   f32 weights
  __shared__ unsigned short btab[15 * 64 * 8];    // 15,360 B banded B-fragments (per-lane, shared by all waves)

  const int tid  = threadIdx.x;
  const int row0 = blockIdx.y * TM;
  const int col0 = blockIdx.x * TN;

  if (tid < KH * KW) sw[tid] = w[tid];

  // ---- stage 78 x 80 input tile as bf16 (zero-fill OOB; cols 78/79 feed only zero-weight band slots) ----
  for (int i = tid; i < LR * (LC / 4); i += 256) {   // 78 * 20 float4 items
    const int r  = i / (LC / 4);
    const int c4 = (i - r * (LC / 4)) * 4;
    const int gr = row0 + r;
    const int gc = col0 + c4;
    float4 v = make_float4(0.f, 0.f, 0.f, 0.f);
    if (gr < HI) {
      const float* p = &x[(long)gr * WI + gc];
      if (gc + 3 < WI) {
        v = *(const float4*)p;
      } else {
        if (gc + 0 < WI) v.x = p[0];
        if (gc + 1 < WI) v.y = p[1];
        if (gc + 2 < WI) v.z = p[2];
        if (gc + 3 < WI) v.w = p[3];
      }
    }
    unsigned int lo = f2bf(v.x) | (f2bf(v.y) << 16);
    unsigned int hi = f2bf(v.z) | (f2bf(v.w) << 16);
    *(uint2*)&sx[r * LSTR + c4] = make_uint2(lo, hi);
  }
  __syncthreads();

  // ---- build banded weight fragments: B_kh[p][j] = w[kh, p-j] if 0<=p-j<15 else 0 ----
  // entry (kh, lane): j = lane&15, p = (lane>>4)*8 + t, t=0..7  (one 16B write each)
  for (int i = tid; i < 15 * 64; i += 256) {
    const int kh = i >> 6;
    const int l  = i & 63;
    const int j  = l & 15;
    const int p0 = (l >> 4) * 8;
    unsigned int d[4];
    #pragma unroll
    for (int t2 = 0; t2 < 4; ++t2) {
      const int idx0 = p0 + 2 * t2 - j;
      const int idx1 = idx0 + 1;
      const unsigned int b0 = (idx0 >= 0 && idx0 < KW) ? f2bf(sw[kh * KW + idx0]) : 0u;
      const unsigned int b1 = (idx1 >= 0 && idx1 < KW) ? f2bf(sw[kh * KW + idx1]) : 0u;
      d[t2] = b0 | (b1 << 16);
    }
    *(uint4*)&btab[i * 8] = make_uint4(d[0], d[1], d[2], d[3]);
  }
  __syncthreads();

  // ---- per-wave setup ----
  const int lane  = tid & 63;
  const int wv    = tid >> 6;                      // wave id 0..3 -> output cols wv*16..+15
  const int arow  = lane & 15;                     // A fragment: row = lane&15
  const int acol  = wv * 16 + (lane >> 4) * 8;     //             k  = (lane>>4)*8 + 0..7
  const unsigned short* abase = &sx[arow * LSTR + acol];

  bf16x8 bfrag[15];
  #pragma unroll
  for (int kh = 0; kh < 15; ++kh)
    bfrag[kh] = *(const bf16x8*)&btab[(kh * 64 + lane) * 8];

  f32x4 acc[4];
  #pragma unroll
  for (int m = 0; m < 4; ++m) acc[m] = (f32x4){0.f, 0.f, 0.f, 0.f};

  // ---- main: 60 ds_read_b128 + 60 MFMA ----
  #pragma unroll
  for (int kh = 0; kh < 15; ++kh) {
    #pragma unroll
    for (int m = 0; m < 4; ++m) {
      bf16x8 a = *(const bf16x8*)(abase + (16 * m + kh) * LSTR);
      acc[m] = __builtin_amdgcn_mfma_f32_16x16x32_bf16(a, bfrag[kh], acc[m], 0, 0, 0);
    }
  }

  // ---- epilogue: C/D layout col=lane&15, row=(lane>>4)*4+reg ----
  const float bs   = bias[0];
  const int   ocol = col0 + wv * 16 + (lane & 15);
  if (ocol < WO) {
    #pragma unroll
    for (int m = 0; m < 4; ++m) {
      const int orow0 = row0 + 16 * m + (lane >> 4) * 4;
      #pragma unroll
      for (int r = 0; r < 4; ++r) {
        const int orow = orow0 + r;
        if (orow < HO) out[(long)orow * WO + ocol] = acc[m][r] + bs;
      }
    }
  }
}

extern "C" void kernel_launch(void* const* d_in, const int* in_sizes, int n_in,
                              void* d_out, int out_size, void* d_ws, size_t ws_size,
                              hipStream_t stream) {
  const float* x    = (const float*)d_in[0];
  const float* w    = (const float*)d_in[1];
  const float* bias = (const float*)d_in[2];
  float* out        = (float*)d_out;

  dim3 grid((WO + TN - 1) / TN, (HO + TM - 1) / TM);   // 64 x 64
  conv2d_mfma<<<grid, dim3(256, 1, 1), 0, stream>>>(x, w, bias, out);
}

// Round 3
// 38.909 us; speedup vs baseline: 7.1642x; 1.1692x over previous
//
#include <hip/hip_runtime.h>

typedef short bf16x8 __attribute__((ext_vector_type(8)));
typedef float f32x4  __attribute__((ext_vector_type(4)));

static constexpr int KH = 15, KW = 15;
static constexpr int HI = 4096, WI = 4096;
static constexpr int HO = HI - KH + 1, WO = WI - KW + 1;   // 4082 x 4082
static constexpr int TM = 64, TN = 128;                    // output tile per block
static constexpr int LR   = TM + KH - 1;                   // 78 staged rows
static constexpr int LC   = TN + 16;                       // 144 staged bf16 cols (A reads touch up to col 143)
static constexpr int LSTR = 152;                           // 304 B/row: 16B-aligned; 76 dw % 32 = 12 -> 2-way max (free)

__device__ __forceinline__ unsigned int f2bf(float f) {
  // round-to-nearest-even f32 -> bf16 bits (no NaN in this problem)
  unsigned int u = __builtin_bit_cast(unsigned int, f);
  return (u + 0x7FFFu + ((u >> 16) & 1u)) >> 16;
}

__global__ __launch_bounds__(512, 8)
void conv2d_mfma2(const float* __restrict__ x, const float* __restrict__ w,
                  const float* __restrict__ bias, float* __restrict__ out) {
  __shared__ unsigned short sx[LR * LSTR];        // 23,712 B bf16 input tile
  __shared__ unsigned short btab[15 * 64 * 8];    // 15,360 B banded B-fragments

  const int tid  = threadIdx.x;
  const int row0 = blockIdx.y * TM;
  const int col0 = blockIdx.x * TN;

  // ---- build banded weight fragments straight from global w (L2 broadcast):
  //      B_kh[p][j] = w[kh, p-j] if 0 <= p-j < 15 else 0
  //      entry (kh, lane): j = lane&15, p = (lane>>4)*8 + t, t=0..7
  for (int i = tid; i < 15 * 64; i += 512) {
    const int kh = i >> 6;
    const int l  = i & 63;
    const int j  = l & 15;
    const int p0 = (l >> 4) * 8;
    unsigned int d[4];
    #pragma unroll
    for (int t2 = 0; t2 < 4; ++t2) {
      const int idx0 = p0 + 2 * t2 - j;
      const int idx1 = idx0 + 1;
      const unsigned int b0 = (idx0 >= 0 && idx0 < KW) ? f2bf(w[kh * KW + idx0]) : 0u;
      const unsigned int b1 = (idx1 >= 0 && idx1 < KW) ? f2bf(w[kh * KW + idx1]) : 0u;
      d[t2] = b0 | (b1 << 16);
    }
    *(uint4*)&btab[i * 8] = make_uint4(d[0], d[1], d[2], d[3]);
  }

  // ---- stage 78 x 144 input tile as bf16 (zero-fill OOB halo) ----
  for (int i = tid; i < LR * (LC / 4); i += 512) {   // 78 * 36 float4 items
    const int r  = i / (LC / 4);
    const int c4 = (i - r * (LC / 4)) * 4;
    const int gr = row0 + r;
    const int gc = col0 + c4;
    float4 v = make_float4(0.f, 0.f, 0.f, 0.f);
    if (gr < HI) {
      const float* p = &x[(long)gr * WI + gc];
      if (gc + 3 < WI) {
        v = *(const float4*)p;
      } else {
        if (gc + 0 < WI) v.x = p[0];
        if (gc + 1 < WI) v.y = p[1];
        if (gc + 2 < WI) v.z = p[2];
        if (gc + 3 < WI) v.w = p[3];
      }
    }
    unsigned int lo = f2bf(v.x) | (f2bf(v.y) << 16);
    unsigned int hi = f2bf(v.z) | (f2bf(v.w) << 16);
    *(uint2*)&sx[r * LSTR + c4] = make_uint2(lo, hi);
  }

  const float bs = bias[0];
  __syncthreads();

  // ---- per-wave setup: wave wv -> output cols [wv*16, wv*16+16), rows m*16.. ----
  const int lane = tid & 63;
  const int wv   = tid >> 6;
  const int arow = lane & 15;                      // A fragment row = lane&15
  const int acol = wv * 16 + (lane >> 4) * 8;      // A fragment k  = (lane>>4)*8 + 0..7
  const unsigned short* abase = &sx[arow * LSTR + acol];
  const unsigned short* bbase = &btab[lane * 8];

  f32x4 acc[4];
  #pragma unroll
  for (int m = 0; m < 4; ++m) acc[m] = (f32x4){0.f, 0.f, 0.f, 0.f};

  // ---- main: per kh: 1 B-read + 4 A-reads + 4 MFMA ----
  #pragma unroll
  for (int kh = 0; kh < 15; ++kh) {
    const bf16x8 b = *(const bf16x8*)(bbase + kh * 64 * 8);
    #pragma unroll
    for (int m = 0; m < 4; ++m) {
      bf16x8 a = *(const bf16x8*)(abase + (16 * m + kh) * LSTR);
      acc[m] = __builtin_amdgcn_mfma_f32_16x16x32_bf16(a, b, acc[m], 0, 0, 0);
    }
  }

  // ---- epilogue: C/D layout col=lane&15, row=(lane>>4)*4+reg ----
  const int ocol = col0 + wv * 16 + (lane & 15);
  if (ocol < WO) {
    #pragma unroll
    for (int m = 0; m < 4; ++m) {
      const int orow0 = row0 + 16 * m + (lane >> 4) * 4;
      #pragma unroll
      for (int r = 0; r < 4; ++r) {
        const int orow = orow0 + r;
        if (orow < HO) out[(long)orow * WO + ocol] = acc[m][r] + bs;
      }
    }
  }
}

extern "C" void kernel_launch(void* const* d_in, const int* in_sizes, int n_in,
                              void* d_out, int out_size, void* d_ws, size_t ws_size,
                              hipStream_t stream) {
  const float* x    = (const float*)d_in[0];
  const float* w    = (const float*)d_in[1];
  const float* bias = (const float*)d_in[2];
  float* out        = (float*)d_out;

  dim3 grid((WO + TN - 1) / TN, (HO + TM - 1) / TM);   // 32 x 64
  conv2d_mfma2<<<grid, dim3(512, 1, 1), 0, stream>>>(x, w, bias, out);
}